// Round 4
// baseline (400.278 us; speedup 1.0000x reference)
//
#include <hip/hip_runtime.h>

// raindrop_fuse: per-batch affine warp (bilinear, zeros padding) of N*K feature
// maps followed by max-reduction over the map axis.
//
// x (40, 64, 100, 252) f32, pairwise_t_matrix (2,5,5,4,4) f32,
// record_len (2,) i32 = [5,3]. rm / time_diffs UNUSED. Out (2,64,100,252) f32.
//
// R3 -> R4: still latency-bound (kernel ~143us, VALUBusy ~27%). Active band
// (40 maps x 64ch x ~25 rows ~ 64 MB) is 2x aggregate L2 => many L3-latency
// stalls. Output rows h,h+1 re-read the same source rows (dpy/dh ~ 1) but
// lived on different CUs => no L1 reuse. Now each thread computes 2 h-rows
// (RPT=2): second row hits L1-warm lines, halving L2/L3 request traffic and
// doubling useful work per outstanding load. Keeps: depth-2 ping-pong
// pipeline, CPT=4 channels/thread, XCD channel-slice swizzle (blockIdx.x=cg),
// column-pair loads with weight-swap edge handling.

#define C_   64
#define H_   100
#define W_   252
#define L_   5
#define K_   5
#define CPT  4           // channels per thread
#define RPT  2           // output h-rows per thread
#define SCALE 1.6f      // DOWNSAMPLE * VOXEL = 4 * 0.4
#define HW_  (H_ * W_)

// 8-byte value, 4-byte alignment (column pair at arbitrary parity).
typedef struct __attribute__((aligned(4))) { float x, y; } f2u;

struct StageW { int o0, o1; float wA0, wB0, wA1, wB1; };

__device__ __forceinline__ void stage_math(const float* __restrict__ thn,
                                           float gx, float gy, StageW& s)
{
    const float sx = thn[0] * gx + thn[1] * gy + thn[2];
    const float sy = thn[3] * gx + thn[4] * gy + thn[5];
    const float px = (sx + 1.0f) * (0.5f * (float)W_) - 0.5f;
    const float py = (sy + 1.0f) * (0.5f * (float)H_) - 0.5f;

    const float x0f = floorf(px), y0f = floorf(py);
    const float wx = px - x0f,   wy = py - y0f;
    const int x0 = (int)x0f, y0 = (int)y0f;
    const int x1 = x0 + 1,   y1 = y0 + 1;

    const bool vx0 = (x0 >= 0) & (x0 < W_);
    const bool vx1 = (x1 >= 0) & (x1 < W_);
    const bool vy0 = (y0 >= 0) & (y0 < H_);
    const bool vy1 = (y1 >= 0) & (y1 < H_);

    const float w00 = (1.0f - wx) * (1.0f - wy) * ((vx0 & vy0) ? 1.0f : 0.0f);
    const float w01 = wx          * (1.0f - wy) * ((vx1 & vy0) ? 1.0f : 0.0f);
    const float w10 = (1.0f - wx) * wy          * ((vx0 & vy1) ? 1.0f : 0.0f);
    const float w11 = wx          * wy          * ((vx1 & vy1) ? 1.0f : 0.0f);

    const int yc0 = min(max(y0, 0), H_ - 1);
    const int yc1 = min(max(y1, 0), H_ - 1);
    const int xp  = min(max(x0, 0), W_ - 2);   // pair base column

    s.o0 = yc0 * W_ + xp;
    s.o1 = yc1 * W_ + xp;

    // If x0 clamped, pair elements map to (x1,x0) swapped; the invalid one has
    // weight 0, so swapping WEIGHTS reproduces exact reference arithmetic.
    const bool sel = (x0 == xp);
    s.wA0 = sel ? w00 : w01;  s.wB0 = sel ? w01 : w00;
    s.wA1 = sel ? w10 : w11;  s.wB1 = sel ? w11 : w10;
}

__device__ __forceinline__ void issue_loads(const float* __restrict__ p,
                                            const StageW s[RPT],
                                            f2u v0[RPT][CPT], f2u v1[RPT][CPT])
{
#pragma unroll
    for (int j = 0; j < CPT; ++j) {
#pragma unroll
        for (int r = 0; r < RPT; ++r) {
            v0[r][j] = *reinterpret_cast<const f2u*>(p + s[r].o0);
            v1[r][j] = *reinterpret_cast<const f2u*>(p + s[r].o1);
        }
        p += HW_;
    }
}

__device__ __forceinline__ void consume(const StageW s[RPT],
                                        const f2u v0[RPT][CPT],
                                        const f2u v1[RPT][CPT],
                                        float acc[RPT][CPT])
{
#pragma unroll
    for (int r = 0; r < RPT; ++r) {
#pragma unroll
        for (int j = 0; j < CPT; ++j) {
            const float v = v0[r][j].x * s[r].wA0 + v0[r][j].y * s[r].wB0 +
                            v1[r][j].x * s[r].wA1 + v1[r][j].y * s[r].wB1;
            acc[r][j] = fmaxf(acc[r][j], v);
        }
    }
}

__global__ __launch_bounds__(256)
void raindrop_fuse_kernel(const float* __restrict__ x,
                          const float* __restrict__ T,      // (B, L, K, 4, 4)
                          const int*   __restrict__ record_len,
                          float* __restrict__ out)
{
    const int cg  = blockIdx.x;        // channel group (x-major => XCD owns slice)
    const int hg  = blockIdx.y;        // h pair: rows 2*hg, 2*hg+1
    const int b   = blockIdx.z;
    const int tid = threadIdx.x;

    __shared__ float th[L_ * K_][6];
    __shared__ int   s_start, s_NK;

    if (tid == 0) {
        int start = 0;
        for (int i = 0; i < b; ++i) start += record_len[i];
        s_start = start * K_;
        s_NK    = record_len[b] * K_;
    }
    if (tid < L_ * K_) {
        const int l = tid / K_, k = tid % K_;
        const float* t = T + (((size_t)(b * L_ + l) * K_ + k) << 4);
        th[tid][0] = t[0];
        th[tid][1] = t[1] * ((float)H_ / (float)W_);
        th[tid][2] = t[3] * (2.0f / (SCALE * (float)W_));
        th[tid][3] = t[4] * ((float)W_ / (float)H_);
        th[tid][4] = t[5];
        th[tid][5] = t[7] * (2.0f / (SCALE * (float)H_));
    }
    __syncthreads();

    const int w = tid;
    if (w >= W_) return;

    const int h0 = hg * RPT;
    const float gx = (2.0f * (float)w + 1.0f) / (float)W_ - 1.0f;
    float gyr[RPT];
#pragma unroll
    for (int r = 0; r < RPT; ++r)
        gyr[r] = (2.0f * (float)(h0 + r) + 1.0f) / (float)H_ - 1.0f;

    const int NK = s_NK;
    const int c0 = cg * CPT;
    const float* __restrict__ base =
        x + ((size_t)s_start * C_ + c0) * (size_t)HW_;

    float acc[RPT][CPT];
#pragma unroll
    for (int r = 0; r < RPT; ++r)
#pragma unroll
        for (int j = 0; j < CPT; ++j) acc[r][j] = -INFINITY;

    // --- 2-deep pipeline, ping-pong buffers A/B ---
    StageW sA[RPT], sB[RPT];
    f2u vA0[RPT][CPT], vA1[RPT][CPT];
    f2u vB0[RPT][CPT], vB1[RPT][CPT];

#pragma unroll
    for (int r = 0; r < RPT; ++r) stage_math(th[0], gx, gyr[r], sA[r]);
    issue_loads(base, sA, vA0, vA1);

    int n = 0;
    while (true) {
        if (n + 1 < NK) {
#pragma unroll
            for (int r = 0; r < RPT; ++r) stage_math(th[n + 1], gx, gyr[r], sB[r]);
            issue_loads(base + (size_t)(n + 1) * C_ * HW_, sB, vB0, vB1);
        }
        consume(sA, vA0, vA1, acc);
        if (++n >= NK) break;

        if (n + 1 < NK) {
#pragma unroll
            for (int r = 0; r < RPT; ++r) stage_math(th[n + 1], gx, gyr[r], sA[r]);
            issue_loads(base + (size_t)(n + 1) * C_ * HW_, sA, vA0, vA1);
        }
        consume(sB, vB0, vB1, acc);
        if (++n >= NK) break;
    }

    const size_t ob = ((size_t)(b * C_ + c0) * H_ + h0) * (size_t)W_ + w;
#pragma unroll
    for (int r = 0; r < RPT; ++r)
#pragma unroll
        for (int j = 0; j < CPT; ++j)
            out[ob + ((size_t)j * H_ + r) * W_] = acc[r][j];
}

extern "C" void kernel_launch(void* const* d_in, const int* in_sizes, int n_in,
                              void* d_out, int out_size, void* d_ws, size_t ws_size,
                              hipStream_t stream) {
    const float* x          = (const float*)d_in[0];
    // d_in[1] = rm (unused), d_in[3] = time_diffs (unused)
    const float* T          = (const float*)d_in[2];
    const int*   record_len = (const int*)d_in[4];
    float*       out        = (float*)d_out;

    const int B = in_sizes[4];               // record_len element count (=2)
    dim3 grid(C_ / CPT, H_ / RPT, B);
    raindrop_fuse_kernel<<<grid, 256, 0, stream>>>(x, T, record_len, out);
}

// Round 5
// 394.491 us; speedup vs baseline: 1.0147x; 1.0147x over previous
//
#include <hip/hip_runtime.h>

// raindrop_fuse: per-batch affine warp (bilinear, zeros padding) of N*K feature
// maps followed by max-reduction over the map axis.
//
// x (40, 64, 100, 252) f32, pairwise_t_matrix (2,5,5,4,4) f32,
// record_len (2,) i32 = [5,3]. rm / time_diffs UNUSED. Out (2,64,100,252) f32.
//
// R4 -> R5: RPT=2 (per-thread row pair) was NEUTRAL — only ~25% request
// reduction (bands share 1 of 2 rows) and it cost 2x value registers.
// Replace with BLOCK-level row tiling: 2D block 64(w) x 4(h). Four adjacent
// output rows now live on one CU; their diagonal source bands overlap 3/4
// rows, so overlapping lines are served from L1 (no VGPR cost). Also halves
// row-break segmentation per wave (64-w span -> ~1.6 y-drift rows vs 6).
// Keeps: CPT=4, depth-2 ping-pong pipeline, column-pair dwordx2 loads with
// weight-swap edge handling, cg-major grid for XCD channel-slice ownership.

#define C_   64
#define H_   100
#define W_   252
#define L_   5
#define K_   5
#define CPT  4           // channels per thread
#define BW_  64          // block w extent
#define BH_  4           // block h extent
#define SCALE 1.6f       // DOWNSAMPLE * VOXEL = 4 * 0.4
#define HW_  (H_ * W_)

// 8-byte value, 4-byte alignment (column pair at arbitrary parity).
typedef struct __attribute__((aligned(4))) { float x, y; } f2u;

struct StageW { int o0, o1; float wA0, wB0, wA1, wB1; };

__device__ __forceinline__ void stage_math(const float* __restrict__ thn,
                                           float gx, float gy, StageW& s)
{
    const float sx = thn[0] * gx + thn[1] * gy + thn[2];
    const float sy = thn[3] * gx + thn[4] * gy + thn[5];
    const float px = (sx + 1.0f) * (0.5f * (float)W_) - 0.5f;
    const float py = (sy + 1.0f) * (0.5f * (float)H_) - 0.5f;

    const float x0f = floorf(px), y0f = floorf(py);
    const float wx = px - x0f,   wy = py - y0f;
    const int x0 = (int)x0f, y0 = (int)y0f;
    const int x1 = x0 + 1,   y1 = y0 + 1;

    const bool vx0 = (x0 >= 0) & (x0 < W_);
    const bool vx1 = (x1 >= 0) & (x1 < W_);
    const bool vy0 = (y0 >= 0) & (y0 < H_);
    const bool vy1 = (y1 >= 0) & (y1 < H_);

    const float w00 = (1.0f - wx) * (1.0f - wy) * ((vx0 & vy0) ? 1.0f : 0.0f);
    const float w01 = wx          * (1.0f - wy) * ((vx1 & vy0) ? 1.0f : 0.0f);
    const float w10 = (1.0f - wx) * wy          * ((vx0 & vy1) ? 1.0f : 0.0f);
    const float w11 = wx          * wy          * ((vx1 & vy1) ? 1.0f : 0.0f);

    const int yc0 = min(max(y0, 0), H_ - 1);
    const int yc1 = min(max(y1, 0), H_ - 1);
    const int xp  = min(max(x0, 0), W_ - 2);   // pair base column

    s.o0 = yc0 * W_ + xp;
    s.o1 = yc1 * W_ + xp;

    // If x0 clamped, pair elements map to (x1,x0) swapped; the invalid one has
    // weight 0, so swapping WEIGHTS reproduces exact reference arithmetic.
    const bool sel = (x0 == xp);
    s.wA0 = sel ? w00 : w01;  s.wB0 = sel ? w01 : w00;
    s.wA1 = sel ? w10 : w11;  s.wB1 = sel ? w11 : w10;
}

__device__ __forceinline__ void issue_loads(const float* __restrict__ p,
                                            const StageW& s,
                                            f2u v0[CPT], f2u v1[CPT])
{
#pragma unroll
    for (int j = 0; j < CPT; ++j) {
        v0[j] = *reinterpret_cast<const f2u*>(p + s.o0);
        v1[j] = *reinterpret_cast<const f2u*>(p + s.o1);
        p += HW_;
    }
}

__device__ __forceinline__ void consume(const StageW& s,
                                        const f2u v0[CPT], const f2u v1[CPT],
                                        float acc[CPT])
{
#pragma unroll
    for (int j = 0; j < CPT; ++j) {
        const float v = v0[j].x * s.wA0 + v0[j].y * s.wB0 +
                        v1[j].x * s.wA1 + v1[j].y * s.wB1;
        acc[j] = fmaxf(acc[j], v);
    }
}

__global__ __launch_bounds__(256)
void raindrop_fuse_kernel(const float* __restrict__ x,
                          const float* __restrict__ T,      // (B, L, K, 4, 4)
                          const int*   __restrict__ record_len,
                          float* __restrict__ out)
{
    const int cg    = blockIdx.x;          // channel group (x-major => XCD slice)
    const int wtile = blockIdx.y & 3;      // 0..3  (w offset = 64*wtile)
    const int hg    = blockIdx.y >> 2;     // 0..24 (h base = 4*hg)
    const int b     = blockIdx.z;
    const int tid   = threadIdx.y * BW_ + threadIdx.x;

    __shared__ float th[L_ * K_][6];
    __shared__ int   s_start, s_NK;

    if (tid == 0) {
        int start = 0;
        for (int i = 0; i < b; ++i) start += record_len[i];
        s_start = start * K_;
        s_NK    = record_len[b] * K_;
    }
    if (tid < L_ * K_) {
        const int l = tid / K_, k = tid % K_;
        const float* t = T + (((size_t)(b * L_ + l) * K_ + k) << 4);
        th[tid][0] = t[0];
        th[tid][1] = t[1] * ((float)H_ / (float)W_);
        th[tid][2] = t[3] * (2.0f / (SCALE * (float)W_));
        th[tid][3] = t[4] * ((float)W_ / (float)H_);
        th[tid][4] = t[5];
        th[tid][5] = t[7] * (2.0f / (SCALE * (float)H_));
    }
    __syncthreads();

    const int w = wtile * BW_ + threadIdx.x;
    const int h = hg * BH_ + threadIdx.y;
    if (w >= W_) return;

    const float gx = (2.0f * (float)w + 1.0f) / (float)W_ - 1.0f;
    const float gy = (2.0f * (float)h + 1.0f) / (float)H_ - 1.0f;

    const int NK = s_NK;
    const int c0 = cg * CPT;
    const float* __restrict__ base =
        x + ((size_t)s_start * C_ + c0) * (size_t)HW_;

    float acc[CPT];
#pragma unroll
    for (int j = 0; j < CPT; ++j) acc[j] = -INFINITY;

    // --- 2-deep pipeline, ping-pong buffers A/B ---
    StageW sA, sB;
    f2u vA0[CPT], vA1[CPT], vB0[CPT], vB1[CPT];

    stage_math(th[0], gx, gy, sA);
    issue_loads(base, sA, vA0, vA1);

    int n = 0;
    while (true) {
        if (n + 1 < NK) {
            stage_math(th[n + 1], gx, gy, sB);
            issue_loads(base + (size_t)(n + 1) * C_ * HW_, sB, vB0, vB1);
        }
        consume(sA, vA0, vA1, acc);
        if (++n >= NK) break;

        if (n + 1 < NK) {
            stage_math(th[n + 1], gx, gy, sA);
            issue_loads(base + (size_t)(n + 1) * C_ * HW_, sA, vA0, vA1);
        }
        consume(sB, vB0, vB1, acc);
        if (++n >= NK) break;
    }

    const size_t ob = ((size_t)(b * C_ + c0) * H_ + h) * (size_t)W_ + w;
#pragma unroll
    for (int j = 0; j < CPT; ++j)
        out[ob + (size_t)j * HW_] = acc[j];
}

extern "C" void kernel_launch(void* const* d_in, const int* in_sizes, int n_in,
                              void* d_out, int out_size, void* d_ws, size_t ws_size,
                              hipStream_t stream) {
    const float* x          = (const float*)d_in[0];
    // d_in[1] = rm (unused), d_in[3] = time_diffs (unused)
    const float* T          = (const float*)d_in[2];
    const int*   record_len = (const int*)d_in[4];
    float*       out        = (float*)d_out;

    const int B = in_sizes[4];               // record_len element count (=2)
    dim3 block(BW_, BH_, 1);
    dim3 grid(C_ / CPT, (W_ + BW_ - 1) / BW_ * (H_ / BH_), B);
    raindrop_fuse_kernel<<<grid, block, 0, stream>>>(x, T, record_len, out);
}